// Round 1
// baseline (922.141 us; speedup 1.0000x reference)
//
#include <hip/hip_runtime.h>
#include <math.h>

#define N_NODES 100000
#define N_EDGES 3200000
#define F_INF   500
#define H_DIM   16
#define C_DIM   3

// workspace layout in 4-byte elements (all 16B-aligned where needed)
#define OFF_CNT   0         // int[100000]
#define OFF_OFFS  100000    // int[100001]
#define OFF_CUR   200004    // int[100000]
#define OFF_DINV  300004    // float[100000]
#define OFF_BSUM  400004    // int[128]
#define OFF_BOFF  400132    // int[128]
#define OFF_CSC   400260    // int[3200000]
#define OFF_H1    3600260   // float[1600000]
#define OFF_A1    5200260   // float[1600000]
#define OFF_H2P   6800260   // float4[100000]

// ---------------- degree histogram ----------------
__global__ void k_hist(const int* __restrict__ dst, int* __restrict__ cnt) {
    int e = blockIdx.x * 256 + threadIdx.x;
    if (e < N_EDGES) atomicAdd(&cnt[dst[e]], 1);
}

// ---------------- scan step 1: block sums (1024 items/block) ----------------
__global__ void k_scan1(const int* __restrict__ cnt, int* __restrict__ bsum) {
    int t = threadIdx.x, b = blockIdx.x;
    int base = b * 1024 + t * 4;
    int s = 0;
#pragma unroll
    for (int u = 0; u < 4; ++u) { int i = base + u; if (i < N_NODES) s += cnt[i]; }
    for (int o = 32; o > 0; o >>= 1) s += __shfl_down(s, o);
    __shared__ int ws4[4];
    int lane = t & 63, wid = t >> 6;
    if (lane == 0) ws4[wid] = s;
    __syncthreads();
    if (t == 0) bsum[b] = ws4[0] + ws4[1] + ws4[2] + ws4[3];
}

// ---------------- scan step 2: scan the 98 block sums ----------------
__global__ void k_scan2(const int* __restrict__ bsum, int* __restrict__ boff) {
    __shared__ int sd[128];
    int t = threadIdx.x;
    int v = (t < 98) ? bsum[t] : 0;
    sd[t] = v;
    __syncthreads();
    for (int o = 1; o < 128; o <<= 1) {
        int y = (t >= o) ? sd[t - o] : 0;
        __syncthreads();
        sd[t] += y;
        __syncthreads();
    }
    boff[t] = sd[t] - v;  // exclusive
}

// ---------------- scan step 3: full exclusive scan, write off/cur/dinv ----------------
__global__ void k_scan3(const int* __restrict__ cnt, const int* __restrict__ boff,
                        int* __restrict__ off, int* __restrict__ cur,
                        float* __restrict__ dinv) {
    int t = threadIdx.x, b = blockIdx.x;
    int base = b * 1024 + t * 4;
    int c[4]; int ts = 0;
#pragma unroll
    for (int u = 0; u < 4; ++u) { int i = base + u; c[u] = (i < N_NODES) ? cnt[i] : 0; ts += c[u]; }
    int inc = ts;
    int lane = t & 63, wid = t >> 6;
    for (int o = 1; o < 64; o <<= 1) {
        int y = __shfl_up(inc, o);
        if (lane >= o) inc += y;
    }
    int excl = inc - ts;
    __shared__ int wsum[4];
    if (lane == 63) wsum[wid] = inc;
    __syncthreads();
    int wbase = 0;
#pragma unroll
    for (int w = 0; w < 4; ++w) if (w < wid) wbase += wsum[w];
    int p = boff[b] + wbase + excl;
    int run = 0;
#pragma unroll
    for (int u = 0; u < 4; ++u) {
        int i = base + u;
        if (i < N_NODES) {
            off[i] = p + run;
            cur[i] = p + run;
            dinv[i] = rsqrtf((float)(c[u] + 1));  // deg = in-deg + self-loop >= 1
            run += c[u];
            if (i == N_NODES - 1) off[N_NODES] = p + run;
        }
    }
}

// ---------------- CSC fill ----------------
__global__ void k_fill(const int* __restrict__ src, const int* __restrict__ dst,
                       int* __restrict__ cur, int* __restrict__ csc) {
    int e = blockIdx.x * 256 + threadIdx.x;
    if (e < N_EDGES) {
        int d = dst[e];
        int pos = atomicAdd(&cur[d], 1);
        csc[pos] = src[e];
    }
}

// ---------------- GEMM1: h1 = X @ W1  [100k x 500]@[500 x 16] ----------------
// 256 rows/block, K-tile = 60, LDS row stride 61 (odd -> bank permutation).
#define KTILE 60
#define KSTRIDE 61
__global__ __launch_bounds__(256) void k_gemm1(const float* __restrict__ x,
                                               const float* __restrict__ W1,
                                               float* __restrict__ h1) {
    __shared__ float xs[256 * KSTRIDE];  // 62.4 KB
    int t = threadIdx.x;
    int row0 = blockIdx.x * 256;
    int row = row0 + t;
    float acc[16];
#pragma unroll
    for (int j = 0; j < 16; ++j) acc[j] = 0.f;
    int rr = t >> 4;   // 0..15: row sub-index for staging
    int cc = t & 15;   // float4 index within k-tile
    for (int k0 = 0; k0 < F_INF; k0 += KTILE) {
        int kw = F_INF - k0; if (kw > KTILE) kw = KTILE;
        int nf4 = kw >> 2;
        __syncthreads();
#pragma unroll
        for (int s = 0; s < 16; ++s) {
            int r = s * 16 + rr;
            int gr = row0 + r;
            if (cc < nf4 && gr < N_NODES) {
                const float4 v = *reinterpret_cast<const float4*>(x + (size_t)gr * F_INF + k0 + cc * 4);
                float* q = xs + r * KSTRIDE + cc * 4;
                q[0] = v.x; q[1] = v.y; q[2] = v.z; q[3] = v.w;
            }
        }
        __syncthreads();
        if (row < N_NODES) {
            for (int kk = 0; kk < kw; ++kk) {
                float xv = xs[t * KSTRIDE + kk];
                const float* Wk = W1 + (k0 + kk) * 16;  // wave-uniform -> s_load
#pragma unroll
                for (int j = 0; j < 16; ++j) acc[j] = fmaf(xv, Wk[j], acc[j]);
            }
        }
    }
    if (row < N_NODES) {
        float4* o = reinterpret_cast<float4*>(h1 + (size_t)row * 16);
        o[0] = make_float4(acc[0],  acc[1],  acc[2],  acc[3]);
        o[1] = make_float4(acc[4],  acc[5],  acc[6],  acc[7]);
        o[2] = make_float4(acc[8],  acc[9],  acc[10], acc[11]);
        o[3] = make_float4(acc[12], acc[13], acc[14], acc[15]);
    }
}

// ---------------- AGG1: a1 = relu(norm-agg(h1) + b1), 16 lanes per node ----------------
__global__ void k_agg1(const float* __restrict__ h1, const int* __restrict__ csc,
                       const int* __restrict__ off, const float* __restrict__ dinv,
                       const float* __restrict__ b1, float* __restrict__ a1) {
    int tid = blockIdx.x * 256 + threadIdx.x;
    int v = tid >> 4, j = tid & 15;
    float dv = dinv[v];
    float acc = dv * h1[v * 16 + j];   // self loop (dv^2 via final *dv)
    int e0 = off[v], e1 = off[v + 1];
    for (int e = e0; e < e1; ++e) {
        int s = csc[e];
        acc = fmaf(dinv[s], h1[s * 16 + j], acc);
    }
    float r = fmaf(acc, dv, b1[j]);
    a1[tid] = fmaxf(r, 0.f);
}

// ---------------- GEMM2: h2p = a1 @ W2 (padded to 4 floats/node) ----------------
__global__ void k_gemm2(const float* __restrict__ a1, const float* __restrict__ W2,
                        float4* __restrict__ h2p) {
    int v = blockIdx.x * 256 + threadIdx.x;
    if (v >= N_NODES) return;
    const float4* ap = reinterpret_cast<const float4*>(a1 + (size_t)v * 16);
    float4 t0 = ap[0], t1 = ap[1], t2 = ap[2], t3 = ap[3];
    float a[16] = {t0.x, t0.y, t0.z, t0.w, t1.x, t1.y, t1.z, t1.w,
                   t2.x, t2.y, t2.z, t2.w, t3.x, t3.y, t3.z, t3.w};
    float c0 = 0.f, c1 = 0.f, c2 = 0.f;
#pragma unroll
    for (int k = 0; k < 16; ++k) {
        c0 = fmaf(a[k], W2[k * 3 + 0], c0);
        c1 = fmaf(a[k], W2[k * 3 + 1], c1);
        c2 = fmaf(a[k], W2[k * 3 + 2], c2);
    }
    h2p[v] = make_float4(c0, c1, c2, 0.f);
}

// ---------------- AGG2 + bias + log_softmax ----------------
__global__ void k_agg2(const float4* __restrict__ h2p, const int* __restrict__ csc,
                       const int* __restrict__ off, const float* __restrict__ dinv,
                       const float* __restrict__ b2, float* __restrict__ out) {
    int v = blockIdx.x * 256 + threadIdx.x;
    if (v >= N_NODES) return;
    float dv = dinv[v];
    float4 hv = h2p[v];
    float ax = dv * hv.x, ay = dv * hv.y, az = dv * hv.z;
    int e0 = off[v], e1 = off[v + 1];
    for (int e = e0; e < e1; ++e) {
        int s = csc[e];
        float ds = dinv[s];
        float4 hs = h2p[s];
        ax = fmaf(ds, hs.x, ax);
        ay = fmaf(ds, hs.y, ay);
        az = fmaf(ds, hs.z, az);
    }
    float z0 = fmaf(ax, dv, b2[0]);
    float z1 = fmaf(ay, dv, b2[1]);
    float z2 = fmaf(az, dv, b2[2]);
    float m = fmaxf(z0, fmaxf(z1, z2));
    float l = logf(expf(z0 - m) + expf(z1 - m) + expf(z2 - m));
    out[v * 3 + 0] = z0 - m - l;
    out[v * 3 + 1] = z1 - m - l;
    out[v * 3 + 2] = z2 - m - l;
}

extern "C" void kernel_launch(void* const* d_in, const int* in_sizes, int n_in,
                              void* d_out, int out_size, void* d_ws, size_t ws_size,
                              hipStream_t stream) {
    (void)in_sizes; (void)n_in; (void)out_size; (void)ws_size;
    const float* x  = (const float*)d_in[0];
    const float* W1 = (const float*)d_in[1];
    const float* b1 = (const float*)d_in[2];
    const float* W2 = (const float*)d_in[3];
    const float* b2 = (const float*)d_in[4];
    const int*   ei = (const int*)d_in[5];
    const int* src = ei;
    const int* dst = ei + N_EDGES;
    float* out = (float*)d_out;

    int* ws = (int*)d_ws;
    int*    cnt  = ws + OFF_CNT;
    int*    off  = ws + OFF_OFFS;
    int*    cur  = ws + OFF_CUR;
    float*  dinv = (float*)(ws + OFF_DINV);
    int*    bsum = ws + OFF_BSUM;
    int*    boff = ws + OFF_BOFF;
    int*    csc  = ws + OFF_CSC;
    float*  h1   = (float*)(ws + OFF_H1);
    float*  a1   = (float*)(ws + OFF_A1);
    float4* h2p  = (float4*)(ws + OFF_H2P);

    hipMemsetAsync(cnt, 0, N_NODES * sizeof(int), stream);

    k_hist <<<(N_EDGES + 255) / 256, 256, 0, stream>>>(dst, cnt);
    k_gemm1<<<(N_NODES + 255) / 256, 256, 0, stream>>>(x, W1, h1);
    k_scan1<<<98, 256, 0, stream>>>(cnt, bsum);
    k_scan2<<<1, 128, 0, stream>>>(bsum, boff);
    k_scan3<<<98, 256, 0, stream>>>(cnt, boff, off, cur, dinv);
    k_fill <<<(N_EDGES + 255) / 256, 256, 0, stream>>>(src, dst, cur, csc);
    k_agg1 <<<(N_NODES * 16) / 256, 256, 0, stream>>>(h1, csc, off, dinv, b1, a1);
    k_gemm2<<<(N_NODES + 255) / 256, 256, 0, stream>>>(a1, W2, h2p);
    k_agg2 <<<(N_NODES + 255) / 256, 256, 0, stream>>>(h2p, csc, off, dinv, b2, out);
}